// Round 6
// baseline (549.166 us; speedup 1.0000x reference)
//
#include <hip/hip_runtime.h>
#include <hip/hip_bf16.h>
#include <stdint.h>

#define B_ 8
#define M_ 2048
#define N_ 2048
#define D_ 1024

typedef __bf16 bf16x8 __attribute__((ext_vector_type(8)));
typedef float f32x4 __attribute__((ext_vector_type(4)));
typedef uint16_t us4 __attribute__((ext_vector_type(4)));
typedef uint16_t us8 __attribute__((ext_vector_type(8)));

__device__ __forceinline__ uint16_t f2b(float f) {
    uint32_t u = __float_as_uint(f);
    return (uint16_t)((u + 0x7FFFu + ((u >> 16) & 1u)) >> 16);
}
__device__ __forceinline__ float b2f(uint16_t h) {
    return __uint_as_float(((uint32_t)h) << 16);
}

__device__ __forceinline__ void gld16(const uint16_t* g, const uint16_t* l) {
    __builtin_amdgcn_global_load_lds(
        (const __attribute__((address_space(1))) uint32_t*)g,
        (__attribute__((address_space(3))) uint32_t*)l,
        16, 0, 0);
}

// ---------------- split x,y into bf16 hi/lo ----------------
__global__ __launch_bounds__(256) void k_split(const float* __restrict__ x,
                                               const float* __restrict__ y,
                                               uint16_t* __restrict__ xh, uint16_t* __restrict__ xl,
                                               uint16_t* __restrict__ yh, uint16_t* __restrict__ yl) {
    const int i = (blockIdx.x * 256 + threadIdx.x) * 4;
    float4 vx = *(const float4*)(x + i);
    float4 vy = *(const float4*)(y + i);
    float fx[4] = {vx.x, vx.y, vx.z, vx.w};
    float fy[4] = {vy.x, vy.y, vy.z, vy.w};
    us4 hx, lx, hy, ly;
#pragma unroll
    for (int k = 0; k < 4; ++k) {
        uint16_t h = f2b(fx[k]);
        hx[k] = h; lx[k] = f2b(fx[k] - b2f(h));
        uint16_t g = f2b(fy[k]);
        hy[k] = g; ly[k] = f2b(fy[k] - b2f(g));
    }
    *(us4*)(xh + i) = hx;
    *(us4*)(xl + i) = lx;
    *(us4*)(yh + i) = hy;
    *(us4*)(yl + i) = ly;
}

// ---------------- GEMM1: e = xh.yh^T + xh.yl^T + xl.yh^T, + softmax partials ----------------
// LDS granule swizzle (BK=32): data granule g of row r stored at g ^ ((r>>1)&3)
// -> conflict-free ds_read_b128 (round 5: SQ_LDS_BANK_CONFLICT 1.7e7 -> 0).
// Epilogue: per-(row, 64-col chunk) partial max & sumexp (fuses k_rowstats).
__global__ __launch_bounds__(256) void k_gemm1(const uint16_t* __restrict__ xh,
                                               const uint16_t* __restrict__ xl,
                                               const uint16_t* __restrict__ yh,
                                               const uint16_t* __restrict__ yl,
                                               float* __restrict__ e,
                                               float* __restrict__ pmax,
                                               float* __restrict__ psum) {
    const int b = blockIdx.z;
    const int m0 = blockIdx.x * 128;
    const int n0 = blockIdx.y * 128;
    __shared__ __align__(16) uint16_t lds[16384];  // 4 tiles of 128x32 bf16

    const int tid = threadIdx.x;
    const int lane = tid & 63;
    const int wid = tid >> 6;
    const int wm = (wid & 1) * 64;
    const int wn = (wid >> 1) * 64;
    const int quad = lane >> 4;
    const int r16 = lane & 15;
    const int swz = quad ^ ((r16 >> 1) & 3);

    const uint16_t* src[4];
    src[0] = xh + ((size_t)b * M_ + m0) * D_;
    src[1] = xl + ((size_t)b * M_ + m0) * D_;
    src[2] = yh + ((size_t)b * N_ + n0) * D_;
    src[3] = yl + ((size_t)b * N_ + n0) * D_;

    f32x4 acc[4][4];
#pragma unroll
    for (int i = 0; i < 4; ++i)
#pragma unroll
        for (int j = 0; j < 4; ++j) acc[i][j] = (f32x4){0.f, 0.f, 0.f, 0.f};

    for (int kt = 0; kt < D_ / 32; ++kt) {
#pragma unroll
        for (int c = 0; c < 8; ++c) {
            const int offbase = c * 2048 + wid * 512;   // wave-uniform LDS dest
            const int tile = offbase >> 12;
            const int o = (offbase & 4095) + lane * 8;
            const int row = o >> 5;
            const int gp = (o & 31) >> 3;
            const int gd = gp ^ ((row >> 1) & 3);
            gld16(src[tile] + (size_t)row * D_ + kt * 32 + gd * 8, &lds[offbase]);
        }
        __syncthreads();

        bf16x8 ah[4], al[4], bh[4], bl[4];
#pragma unroll
        for (int i = 0; i < 4; ++i) {
            const int ra = (wm + i * 16 + r16) * 32 + swz * 8;
            ah[i] = *(const bf16x8*)&lds[ra];
            al[i] = *(const bf16x8*)&lds[4096 + ra];
            const int rb = (wn + i * 16 + r16) * 32 + swz * 8;
            bh[i] = *(const bf16x8*)&lds[8192 + rb];
            bl[i] = *(const bf16x8*)&lds[12288 + rb];
        }
#pragma unroll
        for (int i = 0; i < 4; ++i)
#pragma unroll
            for (int j = 0; j < 4; ++j) {
                acc[i][j] = __builtin_amdgcn_mfma_f32_16x16x32_bf16(ah[i], bh[j], acc[i][j], 0, 0, 0);
                acc[i][j] = __builtin_amdgcn_mfma_f32_16x16x32_bf16(ah[i], bl[j], acc[i][j], 0, 0, 0);
                acc[i][j] = __builtin_amdgcn_mfma_f32_16x16x32_bf16(al[i], bh[j], acc[i][j], 0, 0, 0);
            }
        __syncthreads();
    }

    // epilogue 1: store e
    float* eb = e + (size_t)b * M_ * N_;
#pragma unroll
    for (int i = 0; i < 4; ++i) {
        const int rbase = m0 + wm + i * 16 + quad * 4;
#pragma unroll
        for (int j = 0; j < 4; ++j) {
            const int col = n0 + wn + j * 16 + r16;
#pragma unroll
            for (int r = 0; r < 4; ++r)
                eb[(size_t)(rbase + r) * N_ + col] = acc[i][j][r];
        }
    }

    // epilogue 2: per-row partial softmax stats over this wave's 64 cols.
    // Lane holds rows {wm+i*16+quad*4+r}, cols {wn+j*16+r16}; reduce over r16.
    const int ch = (n0 + wn) >> 6;  // 64-col chunk index, 0..31
#pragma unroll
    for (int i = 0; i < 4; ++i) {
#pragma unroll
        for (int r = 0; r < 4; ++r) {
            float v0 = acc[i][0][r], v1 = acc[i][1][r];
            float v2 = acc[i][2][r], v3 = acc[i][3][r];
            float ml = fmaxf(fmaxf(v0, v1), fmaxf(v2, v3));
#pragma unroll
            for (int s = 1; s < 16; s <<= 1) ml = fmaxf(ml, __shfl_xor(ml, s, 64));
            float sm = __expf(v0 - ml) + __expf(v1 - ml) + __expf(v2 - ml) + __expf(v3 - ml);
#pragma unroll
            for (int s = 1; s < 16; s <<= 1) sm += __shfl_xor(sm, s, 64);
            if (r16 == 0) {
                const size_t row = (size_t)b * M_ + m0 + wm + i * 16 + quad * 4 + r;
                pmax[row * 32 + ch] = ml;
                psum[row * 32 + ch] = sm;
            }
        }
    }
}

// ---------------- stats merge: global max + rescaled sum per row ----------------
__global__ __launch_bounds__(256) void k_stats(const float* __restrict__ pmax,
                                               const float* __restrict__ psum,
                                               float* __restrict__ mx,
                                               float* __restrict__ inv) {
    const int row = blockIdx.x * 256 + threadIdx.x;
    const float* pm = pmax + (size_t)row * 32;
    const float* ps = psum + (size_t)row * 32;
    float gm = pm[0];
#pragma unroll
    for (int c = 1; c < 32; ++c) gm = fmaxf(gm, pm[c]);
    float s = 0.f;
#pragma unroll
    for (int c = 0; c < 32; ++c) s += ps[c] * __expf(pm[c] - gm);
    mx[row] = gm;
    inv[row] = 1.0f / s;
}

// ---------------- transposed softmax: pT[b][n][m] = bf16(exp(e[b][m][n]-mx)*inv) ----------------
__global__ __launch_bounds__(256) void k_texp(const float* __restrict__ e,
                                              const float* __restrict__ mx,
                                              const float* __restrict__ inv,
                                              uint16_t* __restrict__ pT) {
    const int b = blockIdx.z, m0 = blockIdx.x * 64, n0 = blockIdx.y * 64;
    __shared__ float tile[64 * 65];
    const int t = threadIdx.x;
    const float* eb = e + (size_t)b * M_ * N_;
#pragma unroll
    for (int q = 0; q < 4; ++q) {
        const int row = q * 16 + (t >> 4);
        const int c4 = (t & 15) * 4;
        float4 v = *(const float4*)&eb[(size_t)(m0 + row) * N_ + n0 + c4];
        const float mv = mx[b * M_ + m0 + row];
        const float iv = inv[b * M_ + m0 + row];
        tile[row * 65 + c4 + 0] = __expf(v.x - mv) * iv;
        tile[row * 65 + c4 + 1] = __expf(v.y - mv) * iv;
        tile[row * 65 + c4 + 2] = __expf(v.z - mv) * iv;
        tile[row * 65 + c4 + 3] = __expf(v.w - mv) * iv;
    }
    __syncthreads();
    uint16_t* pb = pT + (size_t)b * N_ * M_;
#pragma unroll
    for (int q = 0; q < 2; ++q) {
        const int n = q * 32 + (t >> 3);
        const int mc = (t & 7) * 8;
        us8 o;
#pragma unroll
        for (int k = 0; k < 8; ++k) o[k] = f2b(tile[(mc + k) * 65 + n]);
        *(us8*)&pb[(size_t)(n0 + n) * M_ + m0 + mc] = o;
    }
}

// ---------------- transpose x: xt[b][d][m] = bf16(x[b][m][d]) ----------------
__global__ __launch_bounds__(256) void k_tx(const float* __restrict__ x,
                                            uint16_t* __restrict__ xt) {
    const int b = blockIdx.z, m0 = blockIdx.x * 64, d0 = blockIdx.y * 64;
    __shared__ float tile[64 * 65];
    const int t = threadIdx.x;
    const float* xb = x + (size_t)b * M_ * D_;
#pragma unroll
    for (int q = 0; q < 4; ++q) {
        const int row = q * 16 + (t >> 4);
        const int c4 = (t & 15) * 4;
        float4 v = *(const float4*)&xb[(size_t)(m0 + row) * D_ + d0 + c4];
        tile[row * 65 + c4 + 0] = v.x;
        tile[row * 65 + c4 + 1] = v.y;
        tile[row * 65 + c4 + 2] = v.z;
        tile[row * 65 + c4 + 3] = v.w;
    }
    __syncthreads();
    uint16_t* xtb = xt + (size_t)b * D_ * M_;
#pragma unroll
    for (int q = 0; q < 2; ++q) {
        const int d = q * 32 + (t >> 3);
        const int mc = (t & 7) * 8;
        us8 o;
#pragma unroll
        for (int k = 0; k < 8; ++k) o[k] = f2b(tile[(mc + k) * 65 + d]);
        *(us8*)&xtb[(size_t)(d0 + d) * M_ + m0 + mc] = o;
    }
}

// ---------------- GEMM2: out[b][n][d] = sum_m pT[b][n][m] * xt[b][d][m] ----------------
// BK=64, granule swizzle g ^ (r&7): conflict-free.
__global__ __launch_bounds__(256) void k_gemm2(const uint16_t* __restrict__ pT,
                                               const uint16_t* __restrict__ xt,
                                               float* __restrict__ out) {
    const int b = blockIdx.z;
    const int n0 = blockIdx.x * 128;
    const int d0 = blockIdx.y * 128;
    __shared__ __align__(16) uint16_t lds[16384];  // 2 tiles of 128x64 bf16

    const int tid = threadIdx.x;
    const int lane = tid & 63;
    const int wid = tid >> 6;
    const int wn = (wid & 1) * 64;
    const int wd = (wid >> 1) * 64;
    const int quad = lane >> 4;
    const int r16 = lane & 15;

    const uint16_t* srcA = pT + ((size_t)b * N_ + n0) * M_;
    const uint16_t* srcB = xt + ((size_t)b * D_ + d0) * M_;

    f32x4 acc[4][4];
#pragma unroll
    for (int i = 0; i < 4; ++i)
#pragma unroll
        for (int j = 0; j < 4; ++j) acc[i][j] = (f32x4){0.f, 0.f, 0.f, 0.f};

    for (int kt = 0; kt < M_ / 64; ++kt) {
#pragma unroll
        for (int c = 0; c < 8; ++c) {
            const int offbase = c * 2048 + wid * 512;
            const int tile = offbase >> 13;
            const int o = (offbase & 8191) + lane * 8;
            const int row = o >> 6;
            const int gp = (o & 63) >> 3;
            const int gd = gp ^ (row & 7);
            const uint16_t* sp = tile ? srcB : srcA;
            gld16(sp + (size_t)row * M_ + kt * 64 + gd * 8, &lds[offbase]);
        }
        __syncthreads();

#pragma unroll
        for (int h = 0; h < 2; ++h) {
            const int p = (h * 4 + quad) ^ (r16 & 7);
            bf16x8 a[4], bb[4];
#pragma unroll
            for (int i = 0; i < 4; ++i) {
                a[i]  = *(const bf16x8*)&lds[(wn + i * 16 + r16) * 64 + p * 8];
                bb[i] = *(const bf16x8*)&lds[8192 + (wd + i * 16 + r16) * 64 + p * 8];
            }
#pragma unroll
            for (int i = 0; i < 4; ++i)
#pragma unroll
                for (int j = 0; j < 4; ++j)
                    acc[i][j] = __builtin_amdgcn_mfma_f32_16x16x32_bf16(a[i], bb[j], acc[i][j], 0, 0, 0);
        }
        __syncthreads();
    }

    float* ob = out + (size_t)b * N_ * D_;
#pragma unroll
    for (int i = 0; i < 4; ++i) {
        const int rbase = n0 + wn + i * 16 + quad * 4;
#pragma unroll
        for (int j = 0; j < 4; ++j) {
            const int col = d0 + wd + j * 16 + r16;
#pragma unroll
            for (int r = 0; r < 4; ++r)
                ob[(size_t)(rbase + r) * D_ + col] = acc[i][j][r];
        }
    }
}

extern "C" void kernel_launch(void* const* d_in, const int* in_sizes, int n_in,
                              void* d_out, int out_size, void* d_ws, size_t ws_size,
                              hipStream_t stream) {
    const float* x = (const float*)d_in[0];
    const float* y = (const float*)d_in[1];
    float* out = (float*)d_out;
    char* ws = (char*)d_ws;

    // Per-chunk footprint (g batches), overlays: exactly 32g MiB of ws.
    //   [xh 4g][xl 4g][yh 4g][yl 4g][e 16g]
    // After gemm1 the split region is dead: xt overlays xl; pT overlays yh+yl.
    const size_t MiB = 1024 * 1024;
    int g = 8;
    while (g > 1 && (size_t)g * 32 * MiB > ws_size) g >>= 1;
    if ((size_t)g * 32 * MiB > ws_size) return;  // ws too small: clean fail

    const size_t T = (size_t)g * M_ * D_ * 2;  // one split tensor (4g MiB)
    uint16_t* xh = (uint16_t*)(ws + 0 * T);
    uint16_t* xl = (uint16_t*)(ws + 1 * T);
    uint16_t* yh = (uint16_t*)(ws + 2 * T);
    uint16_t* yl = (uint16_t*)(ws + 3 * T);
    float*    e  = (float*)(ws + 4 * T);
    uint16_t* xt = xl;   // overlays xl (dead after gemm1)
    uint16_t* pT = yh;   // overlays yh+yl (dead after gemm1)

    // Softmax scratch lives at the TAIL of d_out (ws is exactly full).
    // Per chunk: pmax[g*M*32] psum[g*M*32] mx[g*M] inv[g*M] fp32 = 4.13 MiB @ g=8.
    // Safe: within a chunk, gemm1 writes -> k_stats/k_texp read -> gemm2 is the
    // only later writer of d_out (single-stream ordering). Earlier chunks'
    // outputs are below the tail and untouched.
    const size_t outBytes = (size_t)out_size * 4;
    const size_t rowsC = (size_t)g * M_;
    const size_t scratchBytes = rowsC * (32 + 32 + 1 + 1) * 4;
    char* sc = (char*)d_out + outBytes - scratchBytes;
    float* pmax = (float*)sc;
    float* psum = pmax + rowsC * 32;
    float* mx   = psum + rowsC * 32;
    float* inv  = mx + rowsC;

    for (int c0 = 0; c0 < B_; c0 += g) {
        const float* xc = x + (size_t)c0 * M_ * D_;
        const float* yc = y + (size_t)c0 * N_ * D_;
        float* oc = out + (size_t)c0 * N_ * D_;

        hipLaunchKernelGGL(k_split, dim3((g * M_ * D_) / (256 * 4)), dim3(256), 0, stream,
                           xc, yc, xh, xl, yh, yl);
        hipLaunchKernelGGL(k_gemm1, dim3(M_ / 128, N_ / 128, g), dim3(256), 0, stream,
                           xh, xl, yh, yl, e, pmax, psum);
        hipLaunchKernelGGL(k_stats, dim3((g * M_) / 256), dim3(256), 0, stream,
                           pmax, psum, mx, inv);
        hipLaunchKernelGGL(k_texp, dim3(M_ / 64, N_ / 64, g), dim3(256), 0, stream,
                           e, mx, inv, pT);
        hipLaunchKernelGGL(k_tx, dim3(M_ / 64, D_ / 64, g), dim3(256), 0, stream, xc, xt);
        hipLaunchKernelGGL(k_gemm2, dim3(N_ / 128, D_ / 128, g), dim3(256), 0, stream,
                           pT, xt, oc);
    }
}